// Round 2
// baseline (114.579 us; speedup 1.0000x reference)
//
#include <hip/hip_runtime.h>

#define NPTS 32768

typedef _Float16 f16;
typedef _Float16 f16x2 __attribute__((ext_vector_type(2)));
typedef _Float16 f16x8 __attribute__((ext_vector_type(8)));
typedef float f32x2 __attribute__((ext_vector_type(2)));
typedef float f32x4 __attribute__((ext_vector_type(4)));

union H8 { f16x8 v8; f16x2 v2[4]; };

static __device__ __forceinline__ f16x2 pk_fma(f16x2 a, f16x2 b, f16x2 c) {
  return __builtin_elementwise_fma(a, b, c);
}
static __device__ __forceinline__ f16x2 pk_relu(f16x2 a) {
  f16x2 z = {(f16)0.f, (f16)0.f};
  return __builtin_elementwise_max(a, z);
}

// ---------------------------------------------------------------------------
// Kernel 1: per-gas MLP (2->64->64->1), ke[g][n] -> ws.
// A = W2^T held in VGPRs; B = h1^T computed per-lane directly in B-fragment
// layout (no LDS, no barriers). b2 folded into the first MFMA's C operand.
// 74 used gas nets (h2o nets 7,8 never referenced downstream).
// Wave = 512 points (8 passes x 64 pts). 74*64 = 4736 waves = 1184 blocks.
// ---------------------------------------------------------------------------
__global__ __launch_bounds__(256, 2) void k1_mlp(
    const float* __restrict__ t_p, const float* __restrict__ W1,
    const float* __restrict__ b1, const float* __restrict__ W2,
    const float* __restrict__ b2, const float* __restrict__ Wout,
    const float* __restrict__ bout, float* __restrict__ kews)
{
  const int lane = threadIdx.x & 63;
  const int l15  = lane & 15;
  const int quad = lane >> 4;
  const int w    = blockIdx.x * 4 + (threadIdx.x >> 6);
  const int gi   = w >> 6;                 // 0..73
  const int g    = gi + (gi >= 7 ? 2 : 0); // skip unused h2o nets 7,8
  const int pb0  = (w & 63) * 512;

  // ---- A fragments: W2^T. afrag[mt][ks][j] = W2[g][ks*32+quad*8+j][mt*16+l15]
  H8 afrag[4][2];
  const float* W2g = W2 + g * 4096;
  #pragma unroll
  for (int mt = 0; mt < 4; ++mt) {
    #pragma unroll
    for (int ks = 0; ks < 2; ++ks) {
      const float* src = W2g + (ks * 32 + quad * 8) * 64 + mt * 16 + l15;
      #pragma unroll
      for (int i = 0; i < 4; ++i) {
        f16x2 t = { (f16)src[(2 * i) * 64], (f16)src[(2 * i + 1) * 64] };
        afrag[mt][ks].v2[i] = t;
      }
    }
  }

  // ---- layer-1 weights as packed half2: h index = ks*32 + quad*8 + 2i (+1)
  f16x2 w0h[2][4], w1h[2][4], b1h[2][4];
  const float* W1g = W1 + g * 128;   // (2,64): row0 then row1
  const float* b1g = b1 + g * 64;
  #pragma unroll
  for (int ks = 0; ks < 2; ++ks) {
    #pragma unroll
    for (int i = 0; i < 4; ++i) {
      int h = ks * 32 + quad * 8 + 2 * i;
      w0h[ks][i] = f16x2{ (f16)W1g[h],      (f16)W1g[h + 1] };
      w1h[ks][i] = f16x2{ (f16)W1g[64 + h], (f16)W1g[64 + h + 1] };
      b1h[ks][i] = f16x2{ (f16)b1g[h],      (f16)b1g[h + 1] };
    }
  }

  // ---- b2 / Wout per lane: h_out = mt*16 + quad*4 + r  (C-layout rows)
  f32x4 b2q[4];
  f32x2 wq2[4][2];
  #pragma unroll
  for (int mt = 0; mt < 4; ++mt) {
    b2q[mt] = *(const f32x4*)(b2 + g * 64 + mt * 16 + quad * 4);
    f32x4 wv = *(const f32x4*)(Wout + g * 64 + mt * 16 + quad * 4);
    wq2[mt][0] = f32x2{ wv[0], wv[1] };
    wq2[mt][1] = f32x2{ wv[2], wv[3] };
  }
  const float bo = bout[g];

  const float2* tp2 = (const float2*)t_p;
  float* outg = kews + g * NPTS;

  for (int pass = 0; pass < 8; ++pass) {
    const int pb = pb0 + pass * 64;

    // t_p loads (quad-broadcast, 16 consecutive points per ptile)
    float2 xv[4];
    #pragma unroll
    for (int pt = 0; pt < 4; ++pt)
      xv[pt] = tp2[pb + pt * 16 + l15];

    // hoisted x conversions (per point-tile, shared across ks)
    f16x2 x0v[4], x1v[4];
    #pragma unroll
    for (int pt = 0; pt < 4; ++pt) {
      f16 x0 = (f16)xv[pt].x, x1 = (f16)xv[pt].y;
      x0v[pt] = f16x2{ x0, x0 };
      x1v[pt] = f16x2{ x1, x1 };
    }

    // layer 1, directly into B-fragment layout (k = ks*32 + quad*8 + j)
    H8 bfrag[2][4];
    #pragma unroll
    for (int ks = 0; ks < 2; ++ks)
      #pragma unroll
      for (int pt = 0; pt < 4; ++pt)
        #pragma unroll
        for (int i = 0; i < 4; ++i)
          bfrag[ks][pt].v2[i] =
              pk_relu(pk_fma(x0v[pt], w0h[ks][i], pk_fma(x1v[pt], w1h[ks][i], b1h[ks][i])));

    // layer 2: chained MFMA, b2 as the C operand of the first (no acc init)
    f32x4 acc[4][4];
    #pragma unroll
    for (int mt = 0; mt < 4; ++mt)
      #pragma unroll
      for (int pt = 0; pt < 4; ++pt) {
        f32x4 c0 = __builtin_amdgcn_mfma_f32_16x16x32_f16(
            afrag[mt][0].v8, bfrag[0][pt].v8, b2q[mt], 0, 0, 0);
        acc[mt][pt] = __builtin_amdgcn_mfma_f32_16x16x32_f16(
            afrag[mt][1].v8, bfrag[1][pt].v8, c0, 0, 0, 0);
      }

    // layer 3: ke = relu(sum_h relu(h2[h]) * Wout[h] + bout), packed f32 pairs
    float ke[4];
    #pragma unroll
    for (int pt = 0; pt < 4; ++pt) {
      f32x2 p2 = { 0.f, 0.f };
      #pragma unroll
      for (int mt = 0; mt < 4; ++mt) {
        f32x2 z = { 0.f, 0.f };
        f32x2 a0 = { acc[mt][pt][0], acc[mt][pt][1] };
        f32x2 a1 = { acc[mt][pt][2], acc[mt][pt][3] };
        a0 = __builtin_elementwise_max(a0, z);
        a1 = __builtin_elementwise_max(a1, z);
        p2 = __builtin_elementwise_fma(a0, wq2[mt][0], p2);
        p2 = __builtin_elementwise_fma(a1, wq2[mt][1], p2);
      }
      float p = p2[0] + p2[1];
      p += __shfl_xor(p, 16, 64);
      p += __shfl_xor(p, 32, 64);
      ke[pt] = fmaxf(p + bo, 0.f);
    }
    // quad q carries ptile q -> one fully coalesced 64-lane store
    float v = (quad == 0) ? ke[0] : (quad == 1) ? ke[1] : (quad == 2) ? ke[2] : ke[3];
    outg[pb + lane] = v;
  }
}

// ---------------------------------------------------------------------------
// Kernel 2: channel gather + tau_lw / tau_iw.
// tau_gases[c][n] = sum_i ws[CG[c][i]][n] * comp[type(g)][n]
// ---------------------------------------------------------------------------
__device__ const int CCNT[29] = { 6,6,6,2,2,2,2,2,2,2,2,2,2,2,2,2,2,3,3,3,3,3,3,1,1,2,2,3,3 };
__device__ const int CG[29][6] = {
  {0,29,42,51,54,63}, {1,30,43,52,55,64}, {2,31,44,53,56,65},
  {3,57,0,0,0,0},  {4,58,0,0,0,0},  {5,45,0,0,0,0},  {6,46,0,0,0,0},
  {3,59,0,0,0,0},  {4,60,0,0,0,0},  {9,47,0,0,0,0},  {10,48,0,0,0,0},
  {11,61,0,0,0,0}, {12,62,0,0,0,0}, {13,49,0,0,0,0}, {14,50,0,0,0,0},
  {15,66,0,0,0,0}, {16,67,0,0,0,0},
  {17,32,68,0,0,0}, {18,33,69,0,0,0}, {19,34,70,0,0,0},
  {20,35,71,0,0,0}, {21,36,72,0,0,0}, {22,37,73,0,0,0},
  {23,0,0,0,0,0},  {24,0,0,0,0,0},
  {25,38,0,0,0,0}, {26,39,0,0,0,0},
  {27,40,74,0,0,0}, {28,41,75,0,0,0}
};

__global__ __launch_bounds__(256) void k2_gather(
    const float* __restrict__ ws, const float* __restrict__ comp,
    const float* __restrict__ ke_lw, const float* __restrict__ ke_iw,
    float* __restrict__ out)
{
  const int c = blockIdx.x >> 7;
  const int n = ((blockIdx.x & 127) << 8) + threadIdx.x;

  float a = 0.f;
  const int cnt = CCNT[c];
  for (int i = 0; i < cnt; ++i) {
    int g = CG[c][i];
    int t = (g < 29) ? 0 : (g < 42) ? 1 : (g < 51) ? 2 : (g < 54) ? 3 : (g < 63) ? 4 : 5;
    a += ws[g * NPTS + n] * comp[t * NPTS + n];
  }
  out[c * NPTS + n] = a;
  out[29 * NPTS + c * NPTS + n] = ke_lw[c] * comp[6 * NPTS + n];
  out[58 * NPTS + c * NPTS + n] = ke_iw[c] * comp[7 * NPTS + n];
}

// ---------------------------------------------------------------------------
extern "C" void kernel_launch(void* const* d_in, const int* in_sizes, int n_in,
                              void* d_out, int out_size, void* d_ws, size_t ws_size,
                              hipStream_t stream)
{
  const float* t_p   = (const float*)d_in[0];
  const float* comp  = (const float*)d_in[1];
  const float* W1    = (const float*)d_in[2];
  const float* b1    = (const float*)d_in[3];
  const float* W2    = (const float*)d_in[4];
  const float* b2    = (const float*)d_in[5];
  const float* Wout  = (const float*)d_in[6];
  const float* bout  = (const float*)d_in[7];
  const float* ke_lw = (const float*)d_in[8];
  const float* ke_iw = (const float*)d_in[9];
  float* out = (float*)d_out;
  float* ws  = (float*)d_ws;   // 76 * 32768 floats = 9.96 MB

  k1_mlp<<<1184, 256, 0, stream>>>(t_p, W1, b1, W2, b2, Wout, bout, ws);
  k2_gather<<<29 * 128, 256, 0, stream>>>(ws, comp, ke_lw, ke_iw, out);
}

// Round 3
// 113.820 us; speedup vs baseline: 1.0067x; 1.0067x over previous
//
#include <hip/hip_runtime.h>

#define NPTS 32768

typedef _Float16 f16;
typedef _Float16 f16x2 __attribute__((ext_vector_type(2)));
typedef _Float16 f16x8 __attribute__((ext_vector_type(8)));
typedef float f32x2 __attribute__((ext_vector_type(2)));
typedef float f32x4 __attribute__((ext_vector_type(4)));

union H8 { f16x8 v8; f16x2 v2[4]; };

static __device__ __forceinline__ f16x2 pk_fma(f16x2 a, f16x2 b, f16x2 c) {
  return __builtin_elementwise_fma(a, b, c);
}
static __device__ __forceinline__ f16x2 pk_relu(f16x2 a) {
  f16x2 z = {(f16)0.f, (f16)0.f};
  return __builtin_elementwise_max(a, z);
}

// Per used-gas (gi = 0..73) tables:
//   G_T  : composition row index (COMP_IDX of the gas)
//   G_C1 : primary output channel
//   G_C2 : secondary output channel (255 = none; only h2o gases 3,4 have one,
//          from the duplicated entries in H2O_IDX)
__device__ const unsigned char G_T[74] = {
  0,0,0,0,0,0,0, 0,0,0,0,0,0,0,0,0,0,0,0,0,0,0,0,0,0,0,0,   // h2o (g 0..6, 9..28)
  1,1,1,1,1,1,1,1,1,1,1,1,1,                                 // o3
  2,2,2,2,2,2,2,2,2,                                         // co2
  3,3,3,                                                     // n2o
  4,4,4,4,4,4,4,4,4,                                         // ch4
  5,5,5,5,5,5,5,5,5,5,5,5,5                                  // u
};
__device__ const unsigned char G_C1[74] = {
  0,1,2,3,4,5,6, 9,10,11,12,13,14,15,16,17,18,19,20,21,22,23,24,25,26,27,28,
  0,1,2,17,18,19,20,21,22,25,26,27,28,        // O3_CH
  0,1,2,5,6,9,10,13,14,                       // CO2_CH
  0,1,2,                                      // N2O_CH
  0,1,2,3,4,7,8,11,12,                        // CH4_CH
  0,1,2,15,16,17,18,19,20,21,22,27,28         // U_CH
};
__device__ const unsigned char G_C2[74] = {
  255,255,255,7,8,255,255, 255,255,255,255,255,255,255,255,255,255,255,255,
  255,255,255,255,255,255,255,255,
  255,255,255,255,255,255,255,255,255,255,255,255,255,
  255,255,255,255,255,255,255,255,255,
  255,255,255,
  255,255,255,255,255,255,255,255,255,
  255,255,255,255,255,255,255,255,255,255,255,255,255
};

// ---------------------------------------------------------------------------
// k0: zero the gases section of out, write tau_lw / tau_iw.
// ---------------------------------------------------------------------------
__global__ __launch_bounds__(256) void k0_init(
    const float* __restrict__ comp, const float* __restrict__ ke_lw,
    const float* __restrict__ ke_iw, float* __restrict__ out)
{
  const int c = blockIdx.x >> 7;
  const int n = ((blockIdx.x & 127) << 8) + threadIdx.x;
  out[c * NPTS + n] = 0.f;
  out[29 * NPTS + c * NPTS + n] = ke_lw[c] * comp[6 * NPTS + n];
  out[58 * NPTS + c * NPTS + n] = ke_iw[c] * comp[7 * NPTS + n];
}

// ---------------------------------------------------------------------------
// k1: per-gas MLP (2->64->64->1) fused with the channel scatter.
// A = W2^T held in VGPRs; B = h1^T computed per-lane directly in B-fragment
// layout (no LDS, no barriers). b2 folded into the first MFMA's C operand.
// Epilogue: tau = ke * comp[t][n] atomically added to out[ch][n].
// 74 used gas nets; wave = 512 points (8 passes x 64). 4736 waves.
// ---------------------------------------------------------------------------
__global__ __launch_bounds__(256, 2) void k1_mlp(
    const float* __restrict__ t_p, const float* __restrict__ comp,
    const float* __restrict__ W1, const float* __restrict__ b1,
    const float* __restrict__ W2, const float* __restrict__ b2,
    const float* __restrict__ Wout, const float* __restrict__ bout,
    float* __restrict__ out)
{
  const int lane = threadIdx.x & 63;
  const int l15  = lane & 15;
  const int quad = lane >> 4;
  const int w    = blockIdx.x * 4 + (threadIdx.x >> 6);
  const int gi   = w >> 6;                 // 0..73
  const int g    = gi + (gi >= 7 ? 2 : 0); // skip unused h2o nets 7,8
  const int pb0  = (w & 63) * 512;

  const int t  = G_T[gi];
  const int c1 = G_C1[gi];
  const int c2 = G_C2[gi];   // 255 = none

  // ---- A fragments: W2^T. afrag[mt][ks][j] = W2[g][ks*32+quad*8+j][mt*16+l15]
  H8 afrag[4][2];
  const float* W2g = W2 + g * 4096;
  #pragma unroll
  for (int mt = 0; mt < 4; ++mt) {
    #pragma unroll
    for (int ks = 0; ks < 2; ++ks) {
      const float* src = W2g + (ks * 32 + quad * 8) * 64 + mt * 16 + l15;
      #pragma unroll
      for (int i = 0; i < 4; ++i) {
        f16x2 tt = { (f16)src[(2 * i) * 64], (f16)src[(2 * i + 1) * 64] };
        afrag[mt][ks].v2[i] = tt;
      }
    }
  }

  // ---- layer-1 weights as packed half2: h index = ks*32 + quad*8 + 2i (+1)
  f16x2 w0h[2][4], w1h[2][4], b1h[2][4];
  const float* W1g = W1 + g * 128;   // (2,64): row0 then row1
  const float* b1g = b1 + g * 64;
  #pragma unroll
  for (int ks = 0; ks < 2; ++ks) {
    #pragma unroll
    for (int i = 0; i < 4; ++i) {
      int h = ks * 32 + quad * 8 + 2 * i;
      w0h[ks][i] = f16x2{ (f16)W1g[h],      (f16)W1g[h + 1] };
      w1h[ks][i] = f16x2{ (f16)W1g[64 + h], (f16)W1g[64 + h + 1] };
      b1h[ks][i] = f16x2{ (f16)b1g[h],      (f16)b1g[h + 1] };
    }
  }

  // ---- b2 / Wout per lane: h_out = mt*16 + quad*4 + r  (C-layout rows)
  f32x4 b2q[4];
  f32x2 wq2[4][2];
  #pragma unroll
  for (int mt = 0; mt < 4; ++mt) {
    b2q[mt] = *(const f32x4*)(b2 + g * 64 + mt * 16 + quad * 4);
    f32x4 wv = *(const f32x4*)(Wout + g * 64 + mt * 16 + quad * 4);
    wq2[mt][0] = f32x2{ wv[0], wv[1] };
    wq2[mt][1] = f32x2{ wv[2], wv[3] };
  }
  const float bo = bout[g];

  const float2* tp2 = (const float2*)t_p;
  const float* compt = comp + t * NPTS;
  float* out1 = out + c1 * NPTS;
  float* out2 = (c2 == 255) ? nullptr : out + c2 * NPTS;

  for (int pass = 0; pass < 8; ++pass) {
    const int pb = pb0 + pass * 64;

    // t_p loads (quad-broadcast, 16 consecutive points per ptile)
    float2 xv[4];
    #pragma unroll
    for (int pt = 0; pt < 4; ++pt)
      xv[pt] = tp2[pb + pt * 16 + l15];
    // composition for this gas's type, this lane's point
    const float cv = compt[pb + lane];

    f16x2 x0v[4], x1v[4];
    #pragma unroll
    for (int pt = 0; pt < 4; ++pt) {
      f16 x0 = (f16)xv[pt].x, x1 = (f16)xv[pt].y;
      x0v[pt] = f16x2{ x0, x0 };
      x1v[pt] = f16x2{ x1, x1 };
    }

    // layer 1, directly into B-fragment layout (k = ks*32 + quad*8 + j)
    H8 bfrag[2][4];
    #pragma unroll
    for (int ks = 0; ks < 2; ++ks)
      #pragma unroll
      for (int pt = 0; pt < 4; ++pt)
        #pragma unroll
        for (int i = 0; i < 4; ++i)
          bfrag[ks][pt].v2[i] =
              pk_relu(pk_fma(x0v[pt], w0h[ks][i], pk_fma(x1v[pt], w1h[ks][i], b1h[ks][i])));

    // layer 2: chained MFMA, b2 as the C operand of the first (no acc init)
    f32x4 acc[4][4];
    #pragma unroll
    for (int mt = 0; mt < 4; ++mt)
      #pragma unroll
      for (int pt = 0; pt < 4; ++pt) {
        f32x4 c0 = __builtin_amdgcn_mfma_f32_16x16x32_f16(
            afrag[mt][0].v8, bfrag[0][pt].v8, b2q[mt], 0, 0, 0);
        acc[mt][pt] = __builtin_amdgcn_mfma_f32_16x16x32_f16(
            afrag[mt][1].v8, bfrag[1][pt].v8, c0, 0, 0, 0);
      }

    // layer 3: ke = relu(sum_h relu(h2[h]) * Wout[h] + bout)
    float ke[4];
    #pragma unroll
    for (int pt = 0; pt < 4; ++pt) {
      f32x2 p2 = { 0.f, 0.f };
      #pragma unroll
      for (int mt = 0; mt < 4; ++mt) {
        f32x2 z = { 0.f, 0.f };
        f32x2 a0 = { acc[mt][pt][0], acc[mt][pt][1] };
        f32x2 a1 = { acc[mt][pt][2], acc[mt][pt][3] };
        a0 = __builtin_elementwise_max(a0, z);
        a1 = __builtin_elementwise_max(a1, z);
        p2 = __builtin_elementwise_fma(a0, wq2[mt][0], p2);
        p2 = __builtin_elementwise_fma(a1, wq2[mt][1], p2);
      }
      float p = p2[0] + p2[1];
      p += __shfl_xor(p, 16, 64);
      p += __shfl_xor(p, 32, 64);
      ke[pt] = fmaxf(p + bo, 0.f);
    }
    // quad q carries ptile q -> one coalesced 64-lane scatter via atomics
    float v = (quad == 0) ? ke[0] : (quad == 1) ? ke[1] : (quad == 2) ? ke[2] : ke[3];
    float tau = v * cv;
    atomicAdd(&out1[pb + lane], tau);
    if (out2) atomicAdd(&out2[pb + lane], tau);
  }
}

// ---------------------------------------------------------------------------
extern "C" void kernel_launch(void* const* d_in, const int* in_sizes, int n_in,
                              void* d_out, int out_size, void* d_ws, size_t ws_size,
                              hipStream_t stream)
{
  const float* t_p   = (const float*)d_in[0];
  const float* comp  = (const float*)d_in[1];
  const float* W1    = (const float*)d_in[2];
  const float* b1    = (const float*)d_in[3];
  const float* W2    = (const float*)d_in[4];
  const float* b2    = (const float*)d_in[5];
  const float* Wout  = (const float*)d_in[6];
  const float* bout  = (const float*)d_in[7];
  const float* ke_lw = (const float*)d_in[8];
  const float* ke_iw = (const float*)d_in[9];
  float* out = (float*)d_out;

  k0_init<<<29 * 128, 256, 0, stream>>>(comp, ke_lw, ke_iw, out);
  k1_mlp<<<1184, 256, 0, stream>>>(t_p, comp, W1, b1, W2, b2, Wout, bout, out);
}